// Round 9
// baseline (267.821 us; speedup 1.0000x reference)
//
#include <hip/hip_runtime.h>

// LTC via Chebyshev-GEMM, v5: persistent blocks + register-A.
//   out[bt,u] = sA/(1+fs); fs,sA = [BT x 448]*[448 x 512] fp16 GEMM.
// 512 persistent blocks (2/CU). Each block: stage its 64-col B panel (57KB,
// all K) to LDS ONCE, then loop 16 m-tiles. Per m-tile: per-lane Chebyshev
// state IS the MFMA A-fragment (f16x8 regs, advanced by v_pk_fma_f16);
// next tile's X loads issued before the K-loop (latency hidden); K-loop has
// zero barriers / zero global / zero LDS writes. Fixes v4's per-block
// B-restaging serialization (8192 blocks -> 512).

typedef _Float16 f16;
typedef _Float16 f16x8 __attribute__((ext_vector_type(8)));
typedef float f32x4 __attribute__((ext_vector_type(4)));

#if __has_builtin(__builtin_amdgcn_rcpf)
#define RCP(x) __builtin_amdgcn_rcpf(x)
#else
#define RCP(x) (1.0f / (x))
#endif
#if __has_builtin(__builtin_amdgcn_exp2f)
#define EXP2(x) __builtin_amdgcn_exp2f(x)
#else
#define EXP2(x) exp2f(x)
#endif

namespace {
constexpr int D  = 64, U = 256, TT = 1024, BB = 128;
constexpr int BT = BB * TT;              // 131072 GEMM rows
constexpr int NK = 8;                    // degree 7
constexpr int KD = (NK - 1) * 64;        // K = 448
constexpr int ND = 2 * U;                // N = 512
constexpr int NTILE = 16;                // m-tiles per persistent block
constexpr float SCALE = 6.5f;
constexpr size_t WT_BYTES = (size_t)ND * KD * sizeof(f16);
constexpr float L2E = 1.4426950408889634f;
}

// ---------------- kernel 0: per-(u,d) Chebyshev coefficients ----------------
__global__ __launch_bounds__(64) void wgen(
    const float* __restrict__ Aw, const float* __restrict__ sg,
    const float* __restrict__ mu, f16* __restrict__ Wt, float* __restrict__ bias)
{
    const int u = blockIdx.x, d = threadIdx.x;
    const int id = u * 64 + d;
    const float s = sg[id], m = mu[id], a = Aw[id];
    float g[NK], th[NK];
    float q0 = 0.f;
#pragma unroll
    for (int j = 0; j < NK; ++j) {
        th[j] = 3.14159265358979323846f * (float)(2 * j + 1) / (float)(2 * NK);
        float xj = SCALE * cosf(th[j]);
        g[j] = 1.f / (1.f + expf(-s * (xj - m)));
        q0 += g[j];
    }
    q0 *= (1.f / NK);
#pragma unroll
    for (int k = 1; k < NK; ++k) {
        float qk = 0.f;
#pragma unroll
        for (int j = 0; j < NK; ++j) qk += g[j] * cosf((float)k * th[j]);
        qk *= (2.f / NK);
        Wt[(size_t)(2 * u)     * KD + (k - 1) * 64 + d] = (f16)qk;
        Wt[(size_t)(2 * u + 1) * KD + (k - 1) * 64 + d] = (f16)(a * qk);
    }
    float b0 = q0, b1 = a * q0;
#pragma unroll
    for (int off = 1; off < 64; off <<= 1) {
        b0 += __shfl_xor(b0, off);
        b1 += __shfl_xor(b1, off);
    }
    if (d == 0) { bias[2 * u] = 1.f + b0; bias[2 * u + 1] = b1; }
}

// ---------------- persistent fused GEMM, register-A ----------------
#define GLDS16(g, l) __builtin_amdgcn_global_load_lds( \
    (const __attribute__((address_space(1))) void*)(g), \
    (__attribute__((address_space(3))) void*)(l), 16, 0, 0)

__global__ __launch_bounds__(256, 2) void gemm_ltc(
    const float* __restrict__ Xg, const f16* __restrict__ Wt,
    const float* __restrict__ bias, float* __restrict__ outp)
{
    const int tid = threadIdx.x;
    // 512 blocks: nblk = bid>>6 (64 N-cols), mslot = bid&63.
    // X-tile sharers (same mslot, 8 nblks) = bids mslot+64k -> same XCD
    // under round-robin dispatch -> X fetched into each L2 once.
    const int nblk  = blockIdx.x >> 6;
    const int mslot = blockIdx.x & 63;
    const int lane = tid & 63, w = tid >> 6;
    const int wr = w >> 1, wc = w & 1;   // wave = 64 rows x 32 cols
    const int fr = lane & 15, fq = lane >> 4;
    const int r7 = fr & 7;

    __shared__ f16 Bsh[64 * KD];         // 57344 B: B-panel, ALL K

    // ---- stage whole B-panel once (src-col XOR permute, linear dest)
#pragma unroll
    for (int i = 0; i < 14; ++i) {
        const int idx  = tid + 256 * i;          // 16B-unit index, 64*56 total
        const int row  = idx / 56;
        const int slot = idx - row * 56;
        GLDS16(Wt + (size_t)(nblk * 64 + row) * KD + (slot ^ (row & 7)) * 8,
               (f16*)Bsh + (size_t)idx * 8);
    }

    // ---- B read offsets (hoisted): addr = bb[n] + ks*128 + o2[kk]
    int bb[2], o2[2];
#pragma unroll
    for (int n = 0; n < 2; ++n) bb[n] = (wc * 32 + n * 16 + fr) * (KD * 2);
#pragma unroll
    for (int kk = 0; kk < 2; ++kk) o2[kk] = ((kk * 4 + fq) ^ r7) * 16;

    // ---- X addressing: lane covers rows wr*64 + m*16 + fr, d = kk*32+fq*8+(0..7)
    const float* xb0 = Xg + ((size_t)(mslot * NTILE) * 128 + wr * 64 + fr) * 64 + fq * 8;

    // first tile's X loads (in flight with B staging)
    f32x4 xv[4][2][2];
#pragma unroll
    for (int m = 0; m < 4; ++m)
#pragma unroll
        for (int kk = 0; kk < 2; ++kk) {
            const float* p = xb0 + (size_t)m * 16 * 64 + kk * 32;
            xv[m][kk][0] = *(const f32x4*)p;
            xv[m][kk][1] = *(const f32x4*)(p + 4);
        }

    asm volatile("s_waitcnt vmcnt(0)");
    __syncthreads();                     // B ready; only barrier in kernel

    const int ncb = nblk * 64 + wc * 32;
    float bia[2];
#pragma unroll
    for (int n = 0; n < 2; ++n) bia[n] = bias[ncb + n * 16 + fr];
    const bool evenl = !(fr & 1);
    const f16x8 ones = f16x8{(f16)1.f,(f16)1.f,(f16)1.f,(f16)1.f,
                             (f16)1.f,(f16)1.f,(f16)1.f,(f16)1.f};

    for (int it = 0; it < NTILE; ++it) {
        const int mblk = mslot * NTILE + it;

        // ---- convert this tile's X (consumes xv)
        f16x8 tc[4][2], tp[4][2], x2[4][2];
        {
            const float inv = 1.0f / SCALE;
#pragma unroll
            for (int m = 0; m < 4; ++m)
#pragma unroll
                for (int kk = 0; kk < 2; ++kk) {
                    f16x8 t;
#pragma unroll
                    for (int j = 0; j < 4; ++j) {
                        t[j]     = (f16)(xv[m][kk][0][j] * inv);
                        t[4 + j] = (f16)(xv[m][kk][1][j] * inv);
                    }
                    tc[m][kk] = t;
                    x2[m][kk] = t + t;
                    tp[m][kk] = ones;
                }
        }

        // ---- issue next tile's X loads (xv free after convert; WAR safe)
        if (it < NTILE - 1) {
            const float* xb = xb0 + (size_t)(it + 1) * 128 * 64;
#pragma unroll
            for (int m = 0; m < 4; ++m)
#pragma unroll
                for (int kk = 0; kk < 2; ++kk) {
                    const float* p = xb + (size_t)m * 16 * 64 + kk * 32;
                    xv[m][kk][0] = *(const f32x4*)p;
                    xv[m][kk][1] = *(const f32x4*)(p + 4);
                }
        }

        f32x4 acc[4][2];
#pragma unroll
        for (int m = 0; m < 4; ++m)
#pragma unroll
            for (int n = 0; n < 2; ++n) acc[m][n] = f32x4{0.f, 0.f, 0.f, 0.f};

        // ---- K-loop: zero barriers, zero global, zero LDS writes
#pragma unroll
        for (int ks = 0; ks < KD / 64; ++ks) {
            f16x8 bf[2][2];
#pragma unroll
            for (int n = 0; n < 2; ++n)
#pragma unroll
                for (int kk = 0; kk < 2; ++kk)
                    bf[n][kk] = *(const f16x8*)((const char*)Bsh +
                                                bb[n] + ks * 128 + o2[kk]);
#pragma unroll
            for (int kk = 0; kk < 2; ++kk)
#pragma unroll
                for (int m = 0; m < 4; ++m)
#pragma unroll
                    for (int n = 0; n < 2; ++n)
                        acc[m][n] = __builtin_amdgcn_mfma_f32_16x16x32_f16(
                            tc[m][kk], bf[n][kk], acc[m][n], 0, 0, 0);
            if (ks < KD / 64 - 1) {
#pragma unroll
                for (int m = 0; m < 4; ++m)
#pragma unroll
                    for (int kk = 0; kk < 2; ++kk) {
                        f16x8 tn = x2[m][kk] * tc[m][kk] - tp[m][kk];
                        tp[m][kk] = tc[m][kk];
                        tc[m][kk] = tn;
                    }
            }
        }

        // ---- epilogue (prev stores + this tile's X loads are old by now)
        const int growb = mblk * 128 + wr * 64;
#pragma unroll
        for (int m = 0; m < 4; ++m) {
            const int r0 = growb + m * 16 + fq * 4;
#pragma unroll
            for (int n = 0; n < 2; ++n) {
                const int ucol = (ncb + n * 16 + fr) >> 1;
                f32x4 v = acc[m][n];
#pragma unroll
                for (int e = 0; e < 4; ++e) {
                    float full = v[e] + bia[n];
                    float oth  = __shfl_xor(full, 1);
                    if (evenl) outp[(size_t)(r0 + e) * U + ucol] = oth * RCP(full);
                }
            }
        }
    }
}

// ---------------- fallback (proven R3 kernel) for tiny ws ----------------
__global__ __launch_bounds__(256) void ltc_fused2_kernel(
    const float* __restrict__ inp, const float* __restrict__ A,
    const float* __restrict__ sigma, const float* __restrict__ mu,
    const float* __restrict__ x0, float* __restrict__ out)
{
    const int tid = threadIdx.x;
    const int w = tid >> 6, lane = tid & 63;
    const int sl = lane >> 3, um = lane & 7;
    const int bid = blockIdx.x, b = bid >> 3;
    const int ug = (bid & 7) * 32 + w * 8 + um;
    const int d0 = sl * 8;
    __shared__ float sx[2][8 * D];
    float sg[8], cc[8], aa[8];
    {
        const float* sp = sigma + ug * D + d0;
        const float* mp = mu + ug * D + d0;
        const float* ap = A + ug * D + d0;
#pragma unroll
        for (int i = 0; i < 8; ++i) {
            float s_ = sp[i], m_ = mp[i];
            sg[i] = -L2E * s_; cc[i] = L2E * s_ * m_; aa[i] = ap[i];
        }
    }
    float x = x0[ug];
    const float* ib = inp + (size_t)b * TT * D;
    float* ob = out + (size_t)b * TT * U + ug;
    sx[0][tid] = ib[tid]; sx[0][tid + 256] = ib[tid + 256];
    __syncthreads();
    for (int g = 0; g < TT / 8; ++g) {
        float p0 = 0.f, p1 = 0.f;
        if (g < TT / 8 - 1) {
            p0 = ib[(g + 1) * 512 + tid];
            p1 = ib[(g + 1) * 512 + tid + 256];
        }
        const float* sxc = sx[g & 1];
#pragma unroll
        for (int j = 0; j < 8; ++j) {
            const float* xr = sxc + j * D + d0;
            float fs = 0.0f, sA = 0.0f;
#pragma unroll
            for (int i = 0; i < 8; ++i) {
                float e = EXP2(fmaf(sg[i], xr[i], cc[i]));
                float f = RCP(1.0f + e);
                fs += f; sA = fmaf(aa[i], f, sA);
            }
            fs += __shfl_xor(fs, 8);  sA += __shfl_xor(sA, 8);
            fs += __shfl_xor(fs, 16); sA += __shfl_xor(sA, 16);
            fs += __shfl_xor(fs, 32); sA += __shfl_xor(sA, 32);
            float sv = sA * RCP(1.0f + fs);
            float av = EXP2(fmaf(-L2E, fs, -L2E));
            x = fmaf(av, x - sv, sv);
            if (sl == 0) ob[(size_t)(g * 8 + j) * U] = x;
        }
        if (g < TT / 8 - 1) {
            float* sxn = sx[(g + 1) & 1];
            sxn[tid] = p0; sxn[tid + 256] = p1;
        }
        __syncthreads();
    }
}

extern "C" void kernel_launch(void* const* d_in, const int* in_sizes, int n_in,
                              void* d_out, int out_size, void* d_ws, size_t ws_size,
                              hipStream_t stream) {
    const float* inp   = (const float*)d_in[0];
    const float* A     = (const float*)d_in[1];
    const float* sigma = (const float*)d_in[2];
    const float* mu    = (const float*)d_in[3];
    const float* x0    = (const float*)d_in[4];
    float* out = (float*)d_out;

    if (ws_size < WT_BYTES + 4096) {
        ltc_fused2_kernel<<<dim3(BB * 8), dim3(256), 0, stream>>>(inp, A, sigma, mu, x0, out);
        return;
    }

    f16*   Wt   = (f16*)d_ws;
    float* bias = (float*)((char*)d_ws + WT_BYTES);

    wgen<<<dim3(U), dim3(64), 0, stream>>>(A, sigma, mu, Wt, bias);
    gemm_ltc<<<dim3(512), dim3(256), 0, stream>>>(inp, Wt, bias, out);
}

// Round 10
// 223.557 us; speedup vs baseline: 1.1980x; 1.1980x over previous
//
#include <hip/hip_runtime.h>

// LTC via Chebyshev-GEMM, v6: persistent blocks + register-A, spill-proof.
//   out[bt,u] = sA/(1+fs); fs,sA = [BT x 448]*[448 x 512] fp16 GEMM.
// v5 spilled (~210 VGPR demand vs 128 cap -> 1GB scratch traffic). v6 keeps
// the structure but sizes per-lane state to fit 128 regs:
//   - wave tile 32x64 (m-rep 2, n-rep 4; waves stack in M): Chebyshev state
//     tc/tp/x2 = 12 f16x8 = 48 VGPR (was 96); acc = 8 f32x4 = 32.
//   - next-tile X loads issued inside the LAST K-step (tp/x2 dead there),
//     so xv(32) never coexists with full state. Peak ~125 VGPR.
// B 64-col panel (57KB, all K) staged once per persistent block; K-loop has
// zero barriers / zero LDS writes; waves fully independent after one barrier.

typedef _Float16 f16;
typedef _Float16 f16x8 __attribute__((ext_vector_type(8)));
typedef float f32x4 __attribute__((ext_vector_type(4)));

#if __has_builtin(__builtin_amdgcn_rcpf)
#define RCP(x) __builtin_amdgcn_rcpf(x)
#else
#define RCP(x) (1.0f / (x))
#endif
#if __has_builtin(__builtin_amdgcn_exp2f)
#define EXP2(x) __builtin_amdgcn_exp2f(x)
#else
#define EXP2(x) exp2f(x)
#endif

namespace {
constexpr int D  = 64, U = 256, TT = 1024, BB = 128;
constexpr int BT = BB * TT;              // 131072 GEMM rows
constexpr int NK = 8;                    // degree 7
constexpr int KD = (NK - 1) * 64;        // K = 448
constexpr int ND = 2 * U;                // N = 512
constexpr int NTILE = 16;                // m-tiles per persistent block
constexpr float SCALE = 6.5f;
constexpr size_t WT_BYTES = (size_t)ND * KD * sizeof(f16);
constexpr float L2E = 1.4426950408889634f;
}

// ---------------- kernel 0: per-(u,d) Chebyshev coefficients ----------------
__global__ __launch_bounds__(64) void wgen(
    const float* __restrict__ Aw, const float* __restrict__ sg,
    const float* __restrict__ mu, f16* __restrict__ Wt, float* __restrict__ bias)
{
    const int u = blockIdx.x, d = threadIdx.x;
    const int id = u * 64 + d;
    const float s = sg[id], m = mu[id], a = Aw[id];
    float g[NK], th[NK];
    float q0 = 0.f;
#pragma unroll
    for (int j = 0; j < NK; ++j) {
        th[j] = 3.14159265358979323846f * (float)(2 * j + 1) / (float)(2 * NK);
        float xj = SCALE * cosf(th[j]);
        g[j] = 1.f / (1.f + expf(-s * (xj - m)));
        q0 += g[j];
    }
    q0 *= (1.f / NK);
#pragma unroll
    for (int k = 1; k < NK; ++k) {
        float qk = 0.f;
#pragma unroll
        for (int j = 0; j < NK; ++j) qk += g[j] * cosf((float)k * th[j]);
        qk *= (2.f / NK);
        Wt[(size_t)(2 * u)     * KD + (k - 1) * 64 + d] = (f16)qk;
        Wt[(size_t)(2 * u + 1) * KD + (k - 1) * 64 + d] = (f16)(a * qk);
    }
    float b0 = q0, b1 = a * q0;
#pragma unroll
    for (int off = 1; off < 64; off <<= 1) {
        b0 += __shfl_xor(b0, off);
        b1 += __shfl_xor(b1, off);
    }
    if (d == 0) { bias[2 * u] = 1.f + b0; bias[2 * u + 1] = b1; }
}

// ---------------- persistent fused GEMM, register-A ----------------
#define GLDS16(g, l) __builtin_amdgcn_global_load_lds( \
    (const __attribute__((address_space(1))) void*)(g), \
    (__attribute__((address_space(3))) void*)(l), 16, 0, 0)

__global__ __launch_bounds__(256, 2) void gemm_ltc(
    const float* __restrict__ Xg, const f16* __restrict__ Wt,
    const float* __restrict__ bias, float* __restrict__ outp)
{
    const int tid = threadIdx.x;
    // 512 blocks: nblk = bid>>6 (64 N-cols), mslot = bid&63.
    // X-tile sharers (same mslot, 8 nblks) = bids mslot+64k == mslot (mod 8)
    // -> same XCD under round-robin -> X hits that XCD's L2 after first read.
    const int nblk  = blockIdx.x >> 6;
    const int mslot = blockIdx.x & 63;
    const int lane = tid & 63, w = tid >> 6;   // wave w owns rows w*32..w*32+31
    const int fr = lane & 15, fq = lane >> 4;
    const int r7 = fr & 7;

    __shared__ f16 Bsh[64 * KD];         // 57344 B: B-panel, ALL K

    // ---- stage whole B-panel once (src-col XOR permute, linear dest)
#pragma unroll
    for (int i = 0; i < 14; ++i) {
        const int idx  = tid + 256 * i;          // 16B-unit index, 64*56 total
        const int row  = idx / 56;
        const int slot = idx - row * 56;
        GLDS16(Wt + (size_t)(nblk * 64 + row) * KD + (slot ^ (row & 7)) * 8,
               (f16*)Bsh + (size_t)idx * 8);
    }

    // ---- B read offsets: addr = bb[n] + ks*128 + o2[kk]
    int bb[4], o2[2];
#pragma unroll
    for (int n = 0; n < 4; ++n) bb[n] = (n * 16 + fr) * (KD * 2);
#pragma unroll
    for (int kk = 0; kk < 2; ++kk) o2[kk] = ((kk * 4 + fq) ^ r7) * 16;

    // ---- X addressing: lane covers rows w*32 + m*16 + fr, d = kk*32+fq*8+(0..7)
    const float* xb0 = Xg + ((size_t)(mslot * NTILE) * 128 + w * 32 + fr) * 64 + fq * 8;

    // first tile's X loads (in flight with B staging)
    f32x4 xv[2][2][2];
#pragma unroll
    for (int m = 0; m < 2; ++m)
#pragma unroll
        for (int kk = 0; kk < 2; ++kk) {
            const float* p = xb0 + (size_t)m * 16 * 64 + kk * 32;
            xv[m][kk][0] = *(const f32x4*)p;
            xv[m][kk][1] = *(const f32x4*)(p + 4);
        }

    asm volatile("s_waitcnt vmcnt(0)");
    __syncthreads();                     // B ready; only barrier in kernel

    const int ncb = nblk * 64;
    float bia[4];
#pragma unroll
    for (int n = 0; n < 4; ++n) bia[n] = bias[ncb + n * 16 + fr];
    const bool evenl = !(fr & 1);
    const f16x8 ones = f16x8{(f16)1.f,(f16)1.f,(f16)1.f,(f16)1.f,
                             (f16)1.f,(f16)1.f,(f16)1.f,(f16)1.f};

    for (int it = 0; it < NTILE; ++it) {
        const int mblk = mslot * NTILE + it;

        // ---- convert this tile's X (consumes xv; xv free afterwards)
        f16x8 tc[2][2], tp[2][2], x2[2][2];
        {
            const float inv = 1.0f / SCALE;
#pragma unroll
            for (int m = 0; m < 2; ++m)
#pragma unroll
                for (int kk = 0; kk < 2; ++kk) {
                    f16x8 t;
#pragma unroll
                    for (int j = 0; j < 4; ++j) {
                        t[j]     = (f16)(xv[m][kk][0][j] * inv);
                        t[4 + j] = (f16)(xv[m][kk][1][j] * inv);
                    }
                    tc[m][kk] = t;
                    x2[m][kk] = t + t;
                    tp[m][kk] = ones;
                }
        }

        f32x4 acc[2][4];
#pragma unroll
        for (int m = 0; m < 2; ++m)
#pragma unroll
            for (int n = 0; n < 4; ++n) acc[m][n] = f32x4{0.f, 0.f, 0.f, 0.f};

        // ---- K-loop: zero barriers, zero global (except ks==6 prefetch),
        //      zero LDS writes
#pragma unroll
        for (int ks = 0; ks < KD / 64; ++ks) {
            if (ks == KD / 64 - 1 && it < NTILE - 1) {
                // issue next tile's X loads now: tp/x2 are dead (last advance
                // was ks==5), so xv overlaps dead state, not the full set.
                const float* xb = xb0 + (size_t)(it + 1) * 128 * 64;
#pragma unroll
                for (int m = 0; m < 2; ++m)
#pragma unroll
                    for (int kk = 0; kk < 2; ++kk) {
                        const float* p = xb + (size_t)m * 16 * 64 + kk * 32;
                        xv[m][kk][0] = *(const f32x4*)p;
                        xv[m][kk][1] = *(const f32x4*)(p + 4);
                    }
            }
#pragma unroll
            for (int kk = 0; kk < 2; ++kk)
#pragma unroll
                for (int n = 0; n < 4; ++n) {
                    const f16x8 bf = *(const f16x8*)((const char*)Bsh +
                                                     bb[n] + ks * 128 + o2[kk]);
                    acc[0][n] = __builtin_amdgcn_mfma_f32_16x16x32_f16(
                        tc[0][kk], bf, acc[0][n], 0, 0, 0);
                    acc[1][n] = __builtin_amdgcn_mfma_f32_16x16x32_f16(
                        tc[1][kk], bf, acc[1][n], 0, 0, 0);
                }
            if (ks < KD / 64 - 1) {
#pragma unroll
                for (int m = 0; m < 2; ++m)
#pragma unroll
                    for (int kk = 0; kk < 2; ++kk) {
                        f16x8 tn = x2[m][kk] * tc[m][kk] - tp[m][kk];
                        tp[m][kk] = tc[m][kk];
                        tc[m][kk] = tn;
                    }
            }
        }

        // ---- epilogue: pair (2u,2u+1) via shfl_xor(1); out = sA * rcp(1+fs)
        const int growb = mblk * 128 + w * 32;
#pragma unroll
        for (int m = 0; m < 2; ++m) {
            const int r0 = growb + m * 16 + fq * 4;
#pragma unroll
            for (int n = 0; n < 4; ++n) {
                const int ucol = (ncb + n * 16 + fr) >> 1;
                f32x4 v = acc[m][n];
#pragma unroll
                for (int e = 0; e < 4; ++e) {
                    float full = v[e] + bia[n];
                    float oth  = __shfl_xor(full, 1);
                    if (evenl) outp[(size_t)(r0 + e) * U + ucol] = oth * RCP(full);
                }
            }
        }
    }
}

// ---------------- fallback (proven R3 kernel) for tiny ws ----------------
__global__ __launch_bounds__(256) void ltc_fused2_kernel(
    const float* __restrict__ inp, const float* __restrict__ A,
    const float* __restrict__ sigma, const float* __restrict__ mu,
    const float* __restrict__ x0, float* __restrict__ out)
{
    const int tid = threadIdx.x;
    const int w = tid >> 6, lane = tid & 63;
    const int sl = lane >> 3, um = lane & 7;
    const int bid = blockIdx.x, b = bid >> 3;
    const int ug = (bid & 7) * 32 + w * 8 + um;
    const int d0 = sl * 8;
    __shared__ float sx[2][8 * D];
    float sg[8], cc[8], aa[8];
    {
        const float* sp = sigma + ug * D + d0;
        const float* mp = mu + ug * D + d0;
        const float* ap = A + ug * D + d0;
#pragma unroll
        for (int i = 0; i < 8; ++i) {
            float s_ = sp[i], m_ = mp[i];
            sg[i] = -L2E * s_; cc[i] = L2E * s_ * m_; aa[i] = ap[i];
        }
    }
    float x = x0[ug];
    const float* ib = inp + (size_t)b * TT * D;
    float* ob = out + (size_t)b * TT * U + ug;
    sx[0][tid] = ib[tid]; sx[0][tid + 256] = ib[tid + 256];
    __syncthreads();
    for (int g = 0; g < TT / 8; ++g) {
        float p0 = 0.f, p1 = 0.f;
        if (g < TT / 8 - 1) {
            p0 = ib[(g + 1) * 512 + tid];
            p1 = ib[(g + 1) * 512 + tid + 256];
        }
        const float* sxc = sx[g & 1];
#pragma unroll
        for (int j = 0; j < 8; ++j) {
            const float* xr = sxc + j * D + d0;
            float fs = 0.0f, sA = 0.0f;
#pragma unroll
            for (int i = 0; i < 8; ++i) {
                float e = EXP2(fmaf(sg[i], xr[i], cc[i]));
                float f = RCP(1.0f + e);
                fs += f; sA = fmaf(aa[i], f, sA);
            }
            fs += __shfl_xor(fs, 8);  sA += __shfl_xor(sA, 8);
            fs += __shfl_xor(fs, 16); sA += __shfl_xor(sA, 16);
            fs += __shfl_xor(fs, 32); sA += __shfl_xor(sA, 32);
            float sv = sA * RCP(1.0f + fs);
            float av = EXP2(fmaf(-L2E, fs, -L2E));
            x = fmaf(av, x - sv, sv);
            if (sl == 0) ob[(size_t)(g * 8 + j) * U] = x;
        }
        if (g < TT / 8 - 1) {
            float* sxn = sx[(g + 1) & 1];
            sxn[tid] = p0; sxn[tid + 256] = p1;
        }
        __syncthreads();
    }
}

extern "C" void kernel_launch(void* const* d_in, const int* in_sizes, int n_in,
                              void* d_out, int out_size, void* d_ws, size_t ws_size,
                              hipStream_t stream) {
    const float* inp   = (const float*)d_in[0];
    const float* A     = (const float*)d_in[1];
    const float* sigma = (const float*)d_in[2];
    const float* mu    = (const float*)d_in[3];
    const float* x0    = (const float*)d_in[4];
    float* out = (float*)d_out;

    if (ws_size < WT_BYTES + 4096) {
        ltc_fused2_kernel<<<dim3(BB * 8), dim3(256), 0, stream>>>(inp, A, sigma, mu, x0, out);
        return;
    }

    f16*   Wt   = (f16*)d_ws;
    float* bias = (float*)((char*)d_ws + WT_BYTES);

    wgen<<<dim3(U), dim3(64), 0, stream>>>(A, sigma, mu, Wt, bias);
    gemm_ltc<<<dim3(512), dim3(256), 0, stream>>>(inp, Wt, bias, out);
}

// Round 12
// 88.207 us; speedup vs baseline: 3.0363x; 2.5345x over previous
//
#include <hip/hip_runtime.h>

// LTC via Chebyshev-GEMM, v7: v3 structure (proven traffic-clean: FETCH 18MB,
// WRITE 131MB, 0 conflicts) + A-double-buffer -> ONE barrier per K-step.
//   out[bt,u] = sA/(1+fs); fs,sA = [BT x 448]*[448 x 512] fp16 GEMM.
// Per K-step phase: {issue STAGEB(ks+1 -> Bsh[c^1]) FIRST; ds_read af/bf from
// buf c; 32 MFMA; pk_fma T-advance + ds_write A(ks+1) -> Ash[c^1]; barrier}.
// B's L2 latency hides under the phase's MFMA issue; Ash writes target the
// other buffer so the in-place-rebuild serialization of v3 is gone.
// v5/v6 persistent-register-A abandoned: spill + X-refetch traffic (526MB).

typedef _Float16 f16;
typedef _Float16 f16x4 __attribute__((ext_vector_type(4)));
typedef _Float16 f16x8 __attribute__((ext_vector_type(8)));
typedef float f32x4 __attribute__((ext_vector_type(4)));

#if __has_builtin(__builtin_amdgcn_rcpf)
#define RCP(x) __builtin_amdgcn_rcpf(x)
#else
#define RCP(x) (1.0f / (x))
#endif
#if __has_builtin(__builtin_amdgcn_exp2f)
#define EXP2(x) __builtin_amdgcn_exp2f(x)
#else
#define EXP2(x) exp2f(x)
#endif

namespace {
constexpr int D  = 64, U = 256, TT = 1024, BB = 128;
constexpr int BT = BB * TT;              // 131072 GEMM rows
constexpr int NK = 8;                    // degree 7
constexpr int KD = (NK - 1) * 64;        // K = 448
constexpr int ND = 2 * U;                // N = 512
constexpr float SCALE = 6.5f;
constexpr size_t WT_BYTES = (size_t)ND * KD * sizeof(f16);
constexpr float L2E = 1.4426950408889634f;
}

// ---------------- kernel 0: per-(u,d) Chebyshev coefficients ----------------
__global__ __launch_bounds__(64) void wgen(
    const float* __restrict__ Aw, const float* __restrict__ sg,
    const float* __restrict__ mu, f16* __restrict__ Wt, float* __restrict__ bias)
{
    const int u = blockIdx.x, d = threadIdx.x;
    const int id = u * 64 + d;
    const float s = sg[id], m = mu[id], a = Aw[id];
    float g[NK], th[NK];
    float q0 = 0.f;
#pragma unroll
    for (int j = 0; j < NK; ++j) {
        th[j] = 3.14159265358979323846f * (float)(2 * j + 1) / (float)(2 * NK);
        float xj = SCALE * cosf(th[j]);
        g[j] = 1.f / (1.f + expf(-s * (xj - m)));
        q0 += g[j];
    }
    q0 *= (1.f / NK);
#pragma unroll
    for (int k = 1; k < NK; ++k) {
        float qk = 0.f;
#pragma unroll
        for (int j = 0; j < NK; ++j) qk += g[j] * cosf((float)k * th[j]);
        qk *= (2.f / NK);
        Wt[(size_t)(2 * u)     * KD + (k - 1) * 64 + d] = (f16)qk;
        Wt[(size_t)(2 * u + 1) * KD + (k - 1) * 64 + d] = (f16)(a * qk);
    }
    float b0 = q0, b1 = a * q0;
#pragma unroll
    for (int off = 1; off < 64; off <<= 1) {
        b0 += __shfl_xor(b0, off);
        b1 += __shfl_xor(b1, off);
    }
    if (d == 0) { bias[2 * u] = 1.f + b0; bias[2 * u + 1] = b1; }
}

// ---------------- fused GEMM, A-dbuf + B-dbuf, 1 barrier/K-step ----------------
#define GLDS16(g, l) __builtin_amdgcn_global_load_lds( \
    (const __attribute__((address_space(1))) void*)(g), \
    (__attribute__((address_space(3))) void*)(l), 16, 0, 0)

__global__ __launch_bounds__(256) void gemm_ltc(
    const float* __restrict__ Xg, const f16* __restrict__ Wt,
    const float* __restrict__ bias, float* __restrict__ outp)
{
    const int tid = threadIdx.x;
    // XCD swizzle (v3-identical: gave FETCH 18MB)
    const int cpx  = gridDim.x >> 3;
    const int swz  = (blockIdx.x & 7) * cpx + (blockIdx.x >> 3);
    const int nblk = swz & 3;            // 128 N-cols each
    const int mblk = swz >> 2;           // 128 rows each
    const int lane = tid & 63, w = tid >> 6;
    const int wr = w >> 1, wc = w & 1;   // 2x2 waves, 64x64 each
    const int fr = lane & 15, fq = lane >> 4;

    __shared__ f16 Ash[2][128 * 64];     // 16 KB x2
    __shared__ f16 Bsh[2][128 * 64];     // 16 KB x2

    f32x4 acc[4][4];
#pragma unroll
    for (int m = 0; m < 4; ++m)
#pragma unroll
        for (int n = 0; n < 4; ++n) acc[m][n] = f32x4{0.f, 0.f, 0.f, 0.f};

    // ---- B staging (src-col XOR permute, linear glds dest) — v3-identical
    const int srow8 = tid >> 3, slot = tid & 7;
    const int scol  = ((slot ^ (srow8 & 7)) * 8);
    const f16* Bb = Wt + (size_t)(nblk * 128 + srow8) * KD + scol;
#define STAGEB(buf, ks)                                                     \
    {                                                                       \
        _Pragma("unroll")                                                   \
        for (int i = 0; i < 4; ++i)                                         \
            GLDS16(Bb + (size_t)i * 32 * KD + (ks) * 64,                    \
                   &Bsh[buf][i * 2048 + tid * 8]);                          \
    }

    STAGEB(0, 0);

    // ---- x-tile load + Chebyshev init (v3-identical)
    const int xr = tid >> 4, xc = tid & 15;
    const float* xb = Xg + (size_t)(mblk * 128 + xr) * 64 + xc * 4;
    f32x4 xv[8];
#pragma unroll
    for (int i = 0; i < 8; ++i)
        xv[i] = *(const f32x4*)(xb + (size_t)i * 16 * 64);

    f16x4 x2h[8], tp[8], tc[8];
#pragma unroll
    for (int i = 0; i < 8; ++i) {
        const float s = 1.0f / SCALE;
        f16x4 t;
        t[0] = (f16)(xv[i][0] * s); t[1] = (f16)(xv[i][1] * s);
        t[2] = (f16)(xv[i][2] * s); t[3] = (f16)(xv[i][3] * s);
        tc[i]  = t;
        x2h[i] = t + t;
        tp[i]  = f16x4{(f16)1.f, (f16)1.f, (f16)1.f, (f16)1.f};
    }

    // A write addresses (swizzled; v3-identical geometry)
    const int aoff = (((xc >> 1) ^ (xr & 7)) * 16) + (xc & 1) * 8;
#pragma unroll
    for (int i = 0; i < 8; ++i)
        *(f16x4*)((char*)Ash[0] + aoff + (xr + 16 * i) * 128) = tc[i];  // T_1

    __syncthreads();   // drains vmcnt (B0) + lgkm (T_1 visible)

    // ---- MFMA read offsets (v3-identical)
    const int rxr = fr & 7;
    const int arow = (wr * 64 + fr) * 128;
    const int brow = (wc * 64 + fr) * 128;
    int colu[2];
#pragma unroll
    for (int kk = 0; kk < 2; ++kk) colu[kk] = (((kk * 4 + fq) ^ rxr) * 16);

#pragma unroll
    for (int ks = 0; ks < KD / 64; ++ks) {
        const int c = ks & 1;
        if (ks < KD / 64 - 1) STAGEB(c ^ 1, ks + 1);   // issue FIRST (hide L2 lat)
        const char* Ac = (const char*)Ash[c];
        const char* Bc = (const char*)Bsh[c];
#pragma unroll
        for (int kk = 0; kk < 2; ++kk) {
            f16x8 af[4], bf[4];
#pragma unroll
            for (int m = 0; m < 4; ++m)
                af[m] = *(const f16x8*)(Ac + arow + m * 2048 + colu[kk]);
#pragma unroll
            for (int n = 0; n < 4; ++n)
                bf[n] = *(const f16x8*)(Bc + brow + n * 2048 + colu[kk]);
#pragma unroll
            for (int m = 0; m < 4; ++m)
#pragma unroll
                for (int n = 0; n < 4; ++n)
                    acc[m][n] = __builtin_amdgcn_mfma_f32_16x16x32_f16(
                        af[m], bf[n], acc[m][n], 0, 0, 0);
        }
        if (ks < KD / 64 - 1) {
            // T-advance + write NEXT A-tile into the other buffer (no race:
            // Ash[c^1] readers finished before the PREVIOUS barrier)
            char* const an = (char*)Ash[c ^ 1] + aoff;
#pragma unroll
            for (int i = 0; i < 8; ++i) {
                f16x4 tn = x2h[i] * tc[i] - tp[i];
                tp[i] = tc[i]; tc[i] = tn;
                *(f16x4*)(an + (xr + 16 * i) * 128) = tn;
            }
        }
        __syncthreads();   // ONE barrier: A(ks+1) visible + B(ks+1) arrived
    }

    // ---- epilogue (v3-identical): pair (2u,2u+1) via shfl_xor(1)
    const int ncb = nblk * 128 + wc * 64;
    float bia[4];
#pragma unroll
    for (int n = 0; n < 4; ++n) bia[n] = bias[ncb + n * 16 + fr];
    const int growb = mblk * 128 + wr * 64;
    const bool evenl = !(fr & 1);
#pragma unroll
    for (int m = 0; m < 4; ++m) {
        const int r0 = growb + m * 16 + fq * 4;
#pragma unroll
        for (int n = 0; n < 4; ++n) {
            const int ucol = (ncb + n * 16 + fr) >> 1;
            f32x4 v = acc[m][n];
#pragma unroll
            for (int e = 0; e < 4; ++e) {
                float full = v[e] + bia[n];
                float oth  = __shfl_xor(full, 1);
                if (evenl) outp[(size_t)(r0 + e) * U + ucol] = oth * RCP(full);
            }
        }
    }
}

// ---------------- fallback (proven R3 kernel) for tiny ws ----------------
__global__ __launch_bounds__(256) void ltc_fused2_kernel(
    const float* __restrict__ inp, const float* __restrict__ A,
    const float* __restrict__ sigma, const float* __restrict__ mu,
    const float* __restrict__ x0, float* __restrict__ out)
{
    const int tid = threadIdx.x;
    const int w = tid >> 6, lane = tid & 63;
    const int sl = lane >> 3, um = lane & 7;
    const int bid = blockIdx.x, b = bid >> 3;
    const int ug = (bid & 7) * 32 + w * 8 + um;
    const int d0 = sl * 8;
    __shared__ float sx[2][8 * D];
    float sg[8], cc[8], aa[8];
    {
        const float* sp = sigma + ug * D + d0;
        const float* mp = mu + ug * D + d0;
        const float* ap = A + ug * D + d0;
#pragma unroll
        for (int i = 0; i < 8; ++i) {
            float s_ = sp[i], m_ = mp[i];
            sg[i] = -L2E * s_; cc[i] = L2E * s_ * m_; aa[i] = ap[i];
        }
    }
    float x = x0[ug];
    const float* ib = inp + (size_t)b * TT * D;
    float* ob = out + (size_t)b * TT * U + ug;
    sx[0][tid] = ib[tid]; sx[0][tid + 256] = ib[tid + 256];
    __syncthreads();
    for (int g = 0; g < TT / 8; ++g) {
        float p0 = 0.f, p1 = 0.f;
        if (g < TT / 8 - 1) {
            p0 = ib[(g + 1) * 512 + tid];
            p1 = ib[(g + 1) * 512 + tid + 256];
        }
        const float* sxc = sx[g & 1];
#pragma unroll
        for (int j = 0; j < 8; ++j) {
            const float* xr = sxc + j * D + d0;
            float fs = 0.0f, sA = 0.0f;
#pragma unroll
            for (int i = 0; i < 8; ++i) {
                float e = EXP2(fmaf(sg[i], xr[i], cc[i]));
                float f = RCP(1.0f + e);
                fs += f; sA = fmaf(aa[i], f, sA);
            }
            fs += __shfl_xor(fs, 8);  sA += __shfl_xor(sA, 8);
            fs += __shfl_xor(fs, 16); sA += __shfl_xor(sA, 16);
            fs += __shfl_xor(fs, 32); sA += __shfl_xor(sA, 32);
            float sv = sA * RCP(1.0f + fs);
            float av = EXP2(fmaf(-L2E, fs, -L2E));
            x = fmaf(av, x - sv, sv);
            if (sl == 0) ob[(size_t)(g * 8 + j) * U] = x;
        }
        if (g < TT / 8 - 1) {
            float* sxn = sx[(g + 1) & 1];
            sxn[tid] = p0; sxn[tid + 256] = p1;
        }
        __syncthreads();
    }
}

extern "C" void kernel_launch(void* const* d_in, const int* in_sizes, int n_in,
                              void* d_out, int out_size, void* d_ws, size_t ws_size,
                              hipStream_t stream) {
    const float* inp   = (const float*)d_in[0];
    const float* A     = (const float*)d_in[1];
    const float* sigma = (const float*)d_in[2];
    const float* mu    = (const float*)d_in[3];
    const float* x0    = (const float*)d_in[4];
    float* out = (float*)d_out;

    if (ws_size < WT_BYTES + 4096) {
        ltc_fused2_kernel<<<dim3(BB * 8), dim3(256), 0, stream>>>(inp, A, sigma, mu, x0, out);
        return;
    }

    f16*   Wt   = (f16*)d_ws;
    float* bias = (float*)((char*)d_ws + WT_BYTES);

    wgen<<<dim3(U), dim3(64), 0, stream>>>(A, sigma, mu, Wt, bias);
    gemm_ltc<<<dim3((BT / 128) * 4), dim3(256), 0, stream>>>(inp, Wt, bias, out);
}